// Round 3
// baseline (2575.141 us; speedup 1.0000x reference)
//
#include <hip/hip_runtime.h>
#include <math.h>

#define BB 4
#define Cc 64
#define C2 128
#define C6 384
#define HW 65536
#define EPS 1e-6f
#define CST 68   // padded LDS channel stride

// ---------------- K0: RoPE table: tab[r*32+m] = (cos(r*inv[m]), sin(r*inv[m])) ----------------
__global__ void k_tab(float2* __restrict__ tab) {
    int idx = blockIdx.x * 256 + threadIdx.x;   // 8192 entries
    if (idx >= 256 * 32) return;
    int r = idx >> 5, m = idx & 31;
    float inv = expf(-((2.0f * (float)m) / 64.0f) * logf(10000.0f));
    float s, c;
    sincosf((float)r * inv, &s, &c);
    tab[idx] = make_float2(c, s);
}

// ---------------- K0b: transpose w_proj (64x128) -> wpt (128x64) ----------------
__global__ void k_wt(const float* __restrict__ wp, float* __restrict__ wpt) {
    int t = blockIdx.x * 256 + threadIdx.x;
    if (t >= 64 * 128) return;
    int o = t >> 7, cc = t & 127;
    wpt[cc * 64 + o] = wp[o * 128 + cc];
}

// ---------------- K1: fused 1x1 expand + depthwise 3x3 for one batch, rows [r0, r0+R) ----------
// Tile: 16x16 positions (14x14 interior + 1-halo). Thread holds x[64] in regs.
__global__ __launch_bounds__(256) void k_expdw(const float* __restrict__ xb,
                                               const float* __restrict__ wh,
                                               const float* __restrict__ wdw,
                                               float* __restrict__ h2s,
                                               int r0, int R) {
    __shared__ float hs[8 * 256];
    int t = threadIdx.x;
    int tx = t & 15, ty = t >> 4;
    int txi = blockIdx.x % 19, tyi = blockIdx.x / 19;
    int r = r0 + tyi * 14 - 1 + ty;
    int c = txi * 14 - 1 + tx;
    int rcl = min(max(r, 0), 255), ccl = min(max(c, 0), 255);
    float xr[64];
    const float* xp = xb + rcl * 256 + ccl;
#pragma unroll
    for (int i = 0; i < 64; i++) xr[i] = xp[(size_t)i * HW];
    bool interior = (ty >= 1 && ty <= 14 && tx >= 1 && tx <= 14 &&
                     r < r0 + R && r < 256 && c < 256);
    size_t SR = (size_t)R * 256;
    for (int og = 0; og < 48; og++) {
#pragma unroll
        for (int oo = 0; oo < 8; oo++) {
            int o = og * 8 + oo;
            const float* wrow = wh + o * 64;
            float a0 = 0.f, a1 = 0.f;
#pragma unroll
            for (int i = 0; i < 64; i += 2) {
                a0 = fmaf(wrow[i], xr[i], a0);
                a1 = fmaf(wrow[i + 1], xr[i + 1], a1);
            }
            hs[oo * 256 + t] = a0 + a1;
        }
        __syncthreads();
        if (interior) {
#pragma unroll
            for (int oo = 0; oo < 8; oo++) {
                int o = og * 8 + oo;
                const float* wk = wdw + o * 9;
                float acc = 0.f;
#pragma unroll
                for (int dr = -1; dr <= 1; dr++) {
                    int rr = r + dr;
                    if (rr < 0 || rr > 255) continue;
#pragma unroll
                    for (int dc = -1; dc <= 1; dc++) {
                        int cc2 = c + dc;
                        if (cc2 < 0 || cc2 > 255) continue;
                        acc = fmaf(wk[(dr + 1) * 3 + dc + 1],
                                   hs[oo * 256 + (ty + dr) * 16 + tx + dc], acc);
                    }
                }
                h2s[(size_t)o * SR + (size_t)(r - r0) * 256 + c] = acc;
            }
        }
        __syncthreads();
    }
}

// ---------------- K2: fused per-patch: RMS+RoPE(q,k) -> circ-conv -> RMS -> *v -> project ------
__global__ __launch_bounds__(256) void k_patch(const float* __restrict__ h2s,
                                               const float* __restrict__ gq,
                                               const float* __restrict__ gk,
                                               const float* __restrict__ gn,
                                               const float* __restrict__ wpt,
                                               const float2* __restrict__ tab,
                                               float* __restrict__ outb,
                                               int r0, int R) {
    __shared__ float qs[C2 * CST];
    __shared__ float ks[C2 * CST];
    __shared__ float part[256], part2[256];
    __shared__ float sq[64], sk[64], scal[64];
    int t = threadIdx.x;
    int p = blockIdx.x;                 // (R/8)*32 patches
    int prs = p >> 5, pc = p & 31;
    size_t SR = (size_t)R * 256;
    size_t sb = (size_t)(prs * 8) * 256 + pc * 8;
    const float* qg = h2s + sb;
    const float* kg = h2s + 128 * SR + sb;
    const float* vg = h2s + 256 * SR + sb;

    // phase 1: load q,k patch to LDS
    for (int it = 0; it < 8; it++) {
        int l4 = it * 256 + t;
        int c = l4 >> 4, r4 = l4 & 15;
        int i = r4 >> 1, jq = r4 & 1;
        *(float4*)&qs[c * CST + i * 8 + jq * 4] = *(const float4*)(qg + (size_t)c * SR + i * 256 + jq * 4);
        *(float4*)&ks[c * CST + i * 8 + jq * 4] = *(const float4*)(kg + (size_t)c * SR + i * 256 + jq * 4);
    }
    __syncthreads();

    // phase 1b: per-position channel sums of q^2, k^2
    {
        int pos = t & 63, grp = t >> 6;
        float s1 = 0.f, s2 = 0.f;
        for (int c = grp * 32; c < grp * 32 + 32; c++) {
            float a = qs[c * CST + pos]; s1 = fmaf(a, a, s1);
            float e = ks[c * CST + pos]; s2 = fmaf(e, e, s2);
        }
        part[grp * 64 + pos] = s1;
        part2[grp * 64 + pos] = s2;
    }
    __syncthreads();
    if (t < 64) {
        sq[t] = rsqrtf((part[t] + part[64 + t] + part[128 + t] + part[192 + t]) * (1.f / 128.f) + EPS);
    } else if (t < 128) {
        int u = t - 64;
        sk[u] = rsqrtf((part2[u] + part2[64 + u] + part2[128 + u] + part2[192 + u]) * (1.f / 128.f) + EPS);
    }
    __syncthreads();

    // phase 1c: RMS-scale + RoPE in place (pairs 2m,2m+1)
    for (int u = 0; u < 16; u++) {
        int task = u * 256 + t;
        int m = task >> 6, pos = task & 63;
        int i = pos >> 3, j = pos & 7;
        float2 cs = (m < 32) ? tab[(r0 + prs * 8 + i) * 32 + m]
                             : tab[(pc * 8 + j) * 32 + (m - 32)];
        float sqp = sq[pos], skp = sk[pos];
        float q0 = qs[(2 * m) * CST + pos], q1 = qs[(2 * m + 1) * CST + pos];
        float y0 = gq[2 * m] * q0 * sqp, y1 = gq[2 * m + 1] * q1 * sqp;
        qs[(2 * m) * CST + pos] = y0 * cs.x - y1 * cs.y;
        qs[(2 * m + 1) * CST + pos] = y1 * cs.x + y0 * cs.y;
        float k0 = ks[(2 * m) * CST + pos], k1 = ks[(2 * m + 1) * CST + pos];
        float z0 = gk[2 * m] * k0 * skp, z1 = gk[2 * m + 1] * k1 * skp;
        ks[(2 * m) * CST + pos] = z0 * cs.x - z1 * cs.y;
        ks[(2 * m + 1) * CST + pos] = z1 * cs.x + z0 * cs.y;
    }
    __syncthreads();

    // phase 2: circular conv rows -> registers (task = (c, m), 4 per thread)
    float creg[4][8];
    for (int g4 = 0; g4 < 4; g4++) {
        int task = g4 * 256 + t;
        int c = task >> 3, m = task & 7;
        float o8[8] = {0, 0, 0, 0, 0, 0, 0, 0};
#pragma unroll
        for (int i = 0; i < 8; i++) {
            const float* qr = &qs[c * CST + i * 8];
            float4 qa = *(const float4*)qr, qb = *(const float4*)(qr + 4);
            float qq[8] = {qa.x, qa.y, qa.z, qa.w, qb.x, qb.y, qb.z, qb.w};
            int kr = (m - i) & 7;
            const float* krp = &ks[c * CST + kr * 8];
            float4 ka = *(const float4*)krp, kb2 = *(const float4*)(krp + 4);
            float kk[8] = {ka.x, ka.y, ka.z, ka.w, kb2.x, kb2.y, kb2.z, kb2.w};
#pragma unroll
            for (int n = 0; n < 8; n++)
#pragma unroll
                for (int j = 0; j < 8; j++)
                    o8[n] = fmaf(qq[j], kk[(n - j) & 7], o8[n]);
        }
#pragma unroll
        for (int n = 0; n < 8; n++) creg[g4][n] = o8[n];
    }
    __syncthreads();

    // phase 3: store corr over qs
    for (int g4 = 0; g4 < 4; g4++) {
        int task = g4 * 256 + t;
        int c = task >> 3, m = task & 7;
        *(float4*)&qs[c * CST + m * 8] =
            make_float4(creg[g4][0], creg[g4][1], creg[g4][2], creg[g4][3]);
        *(float4*)&qs[c * CST + m * 8 + 4] =
            make_float4(creg[g4][4], creg[g4][5], creg[g4][6], creg[g4][7]);
    }
    __syncthreads();

    // phase 4: per-position sum of corr^2 over channels
    {
        int pos = t & 63, q4 = t >> 6;
        float ssum = 0.f;
        for (int c = q4 * 32; c < q4 * 32 + 32; c++) {
            float v = qs[c * CST + pos];
            ssum = fmaf(v, v, ssum);
        }
        part[q4 * 64 + pos] = ssum;
    }
    __syncthreads();
    if (t < 64) {
        float s = part[t] + part[64 + t] + part[128 + t] + part[192 + t];
        scal[t] = rsqrtf(s * (1.0f / 128.f) + EPS);
    }
    __syncthreads();

    // phase 5: tmod in place: qs[c][pos] = corr*scal[pos]*gn[c]*v[c][pos]
    for (int it = 0; it < 8; it++) {
        int l4 = it * 256 + t;
        int c = l4 >> 4, r4 = l4 & 15;
        int i = r4 >> 1, jq = r4 & 1;
        float4 vv = *(const float4*)(vg + (size_t)c * SR + i * 256 + jq * 4);
        float4 sc4 = *(const float4*)&scal[r4 * 4];
        float g = gn[c];
        float4 cu = *(float4*)&qs[c * CST + r4 * 4];
        cu.x = cu.x * sc4.x * g * vv.x;
        cu.y = cu.y * sc4.y * g * vv.y;
        cu.z = cu.z * sc4.z * g * vv.z;
        cu.w = cu.w * sc4.w * g * vv.w;
        *(float4*)&qs[c * CST + r4 * 4] = cu;
    }
    __syncthreads();

    // phase 6: project 128->64, stage to ks as out_s[pos*CST + o]
    {
        int o = t & 63, pg = t >> 6;
        float acc[16];
#pragma unroll
        for (int u = 0; u < 16; u++) acc[u] = 0.f;
        for (int c = 0; c < C2; c++) {
            float w = wpt[c * 64 + o];
            const float* tp = &qs[c * CST + pg * 16];
#pragma unroll
            for (int u4 = 0; u4 < 4; u4++) {
                float4 tv = *(const float4*)(tp + u4 * 4);
                acc[u4 * 4 + 0] = fmaf(w, tv.x, acc[u4 * 4 + 0]);
                acc[u4 * 4 + 1] = fmaf(w, tv.y, acc[u4 * 4 + 1]);
                acc[u4 * 4 + 2] = fmaf(w, tv.z, acc[u4 * 4 + 2]);
                acc[u4 * 4 + 3] = fmaf(w, tv.w, acc[u4 * 4 + 3]);
            }
        }
#pragma unroll
        for (int u = 0; u < 16; u++) ks[(pg * 16 + u) * CST + o] = acc[u];
    }
    __syncthreads();

    // phase 7: coalesced out write
    float* og = outb + (size_t)r0 * 256 + sb;
    for (int it = 0; it < 4; it++) {
        int l4 = it * 256 + t;
        int o = l4 >> 4, r4 = l4 & 15;
        int i = r4 >> 1, jq = r4 & 1;
        int p0 = i * 8 + jq * 4;
        float4 vv = make_float4(ks[(p0 + 0) * CST + o], ks[(p0 + 1) * CST + o],
                                ks[(p0 + 2) * CST + o], ks[(p0 + 3) * CST + o]);
        *(float4*)(og + (size_t)o * HW + i * 256 + jq * 4) = vv;
    }
}

extern "C" void kernel_launch(void* const* d_in, const int* in_sizes, int n_in,
                              void* d_out, int out_size, void* d_ws, size_t ws_size,
                              hipStream_t stream) {
    const float* x   = (const float*)d_in[0];
    const float* wh  = (const float*)d_in[1];
    const float* wdw = (const float*)d_in[2];
    const float* wp  = (const float*)d_in[3];
    const float* gn  = (const float*)d_in[4];
    const float* gq  = (const float*)d_in[5];
    const float* gk  = (const float*)d_in[6];
    float* out = (float*)d_out;

    // ws layout (floats): tab[16384] | wpt[8192] | h2s[384 * R * 256]
    size_t avail = ws_size / 4;
    if (avail < (size_t)24576 + (size_t)C6 * 8 * 256) return;  // need at least R=8
    size_t rows_cap = (avail - 24576) / ((size_t)C6 * 256);
    int R = (rows_cap >= 256) ? 256 : (int)(rows_cap & ~(size_t)7);

    float* ws = (float*)d_ws;
    float2* tab = (float2*)ws;
    float* wpt  = ws + 16384;
    float* h2s  = ws + 24576;

    k_tab<<<32, 256, 0, stream>>>(tab);
    k_wt<<<32, 256, 0, stream>>>(wp, wpt);
    for (int b = 0; b < BB; b++) {
        const float* xb = x + (size_t)b * Cc * HW;
        float* outb = out + (size_t)b * Cc * HW;
        for (int r0 = 0; r0 < 256; r0 += R) {
            int Rc = (256 - r0 < R) ? (256 - r0) : R;
            int tiles_y = (Rc + 13) / 14;
            k_expdw<<<tiles_y * 19, 256, 0, stream>>>(xb, wh, wdw, h2s, r0, Rc);
            k_patch<<<(Rc / 8) * 32, 256, 0, stream>>>(h2s, gq, gk, gn, wpt, tab, outb, r0, Rc);
        }
    }
}

// Round 4
// 1189.916 us; speedup vs baseline: 2.1641x; 2.1641x over previous
//
#include <hip/hip_runtime.h>
#include <math.h>

#define BB 4
#define Cc 64
#define C2 128
#define C6 384
#define HW 65536
#define EPS 1e-6f
#define CST 68      // padded LDS channel stride
#define OSPLIT 4    // output-channel split across blocks
#define OGPB 12     // 48/OSPLIT og-groups (of 8 channels) per block

// ---------------- K0: RoPE table: tab[r*32+m] = (cos(r*inv[m]), sin(r*inv[m])) ----------------
__global__ void k_tab(float2* __restrict__ tab) {
    int idx = blockIdx.x * 256 + threadIdx.x;   // 8192 entries
    if (idx >= 256 * 32) return;
    int r = idx >> 5, m = idx & 31;
    float inv = expf(-((2.0f * (float)m) / 64.0f) * logf(10000.0f));
    float s, c;
    sincosf((float)r * inv, &s, &c);
    tab[idx] = make_float2(c, s);
}

// ---------------- K0b: transpose w_proj (64x128) -> wpt (128x64) ----------------
__global__ void k_wt(const float* __restrict__ wp, float* __restrict__ wpt) {
    int t = blockIdx.x * 256 + threadIdx.x;
    if (t >= 64 * 128) return;
    int o = t >> 7, cc = t & 127;
    wpt[cc * 64 + o] = wp[o * 128 + cc];
}

// ---------------- K1: fused 1x1 expand + depthwise 3x3, rows [r0, r0+R), 96 out-ch per block --
// Tile: 16x16 positions (14x14 interior + 1-halo). Thread holds x[64] in regs (launch_bounds
// (256,2) -> VGPR cap 256, prevents the 40-VGPR spill seen in R3).
__global__ __launch_bounds__(256, 2) void k_expdw(const float* __restrict__ xb,
                                                  const float* __restrict__ wh,
                                                  const float* __restrict__ wdw,
                                                  float* __restrict__ h2s,
                                                  int r0, int R, int tiles_y) {
    __shared__ float hs[8 * 256];
    int t = threadIdx.x;
    int tx = t & 15, ty = t >> 4;
    int blk = blockIdx.x;
    int txi = blk % 19;
    int rest = blk / 19;
    int tyi = rest % tiles_y;
    int os = rest / tiles_y;
    int r = r0 + tyi * 14 - 1 + ty;
    int c = txi * 14 - 1 + tx;
    int rcl = min(max(r, 0), 255), ccl = min(max(c, 0), 255);
    float xr[64];
    const float* xp = xb + rcl * 256 + ccl;
#pragma unroll
    for (int i = 0; i < 64; i++) xr[i] = xp[(size_t)i * HW];
    bool interior = (ty >= 1 && ty <= 14 && tx >= 1 && tx <= 14 &&
                     r < r0 + R && r < 256 && c < 256);
    size_t SR = (size_t)R * 256;
    for (int ogl = 0; ogl < OGPB; ogl++) {
        int og = os * OGPB + ogl;
#pragma unroll
        for (int oo = 0; oo < 8; oo++) {
            int o = og * 8 + oo;
            const float* wrow = wh + o * 64;
            float a0 = 0.f, a1 = 0.f;
#pragma unroll
            for (int i = 0; i < 64; i += 2) {
                a0 = fmaf(wrow[i], xr[i], a0);
                a1 = fmaf(wrow[i + 1], xr[i + 1], a1);
            }
            hs[oo * 256 + t] = a0 + a1;
        }
        __syncthreads();
        if (interior) {
#pragma unroll
            for (int oo = 0; oo < 8; oo++) {
                int o = og * 8 + oo;
                const float* wk = wdw + o * 9;
                float acc = 0.f;
#pragma unroll
                for (int dr = -1; dr <= 1; dr++) {
                    int rr = r + dr;
                    if (rr < 0 || rr > 255) continue;
#pragma unroll
                    for (int dc = -1; dc <= 1; dc++) {
                        int cc2 = c + dc;
                        if (cc2 < 0 || cc2 > 255) continue;
                        acc = fmaf(wk[(dr + 1) * 3 + dc + 1],
                                   hs[oo * 256 + (ty + dr) * 16 + tx + dc], acc);
                    }
                }
                h2s[(size_t)o * SR + (size_t)(r - r0) * 256 + c] = acc;
            }
        }
        __syncthreads();
    }
}

// ---------------- K2: fused per-patch: RMS+RoPE(q,k) -> circ-conv -> RMS -> *v -> project ------
__global__ __launch_bounds__(256, 2) void k_patch(const float* __restrict__ h2s,
                                                  const float* __restrict__ gq,
                                                  const float* __restrict__ gk,
                                                  const float* __restrict__ gn,
                                                  const float* __restrict__ wpt,
                                                  const float2* __restrict__ tab,
                                                  float* __restrict__ outb,
                                                  int r0, int R) {
    __shared__ float qs[C2 * CST];
    __shared__ float ks[C2 * CST];
    __shared__ float part[256], part2[256];
    __shared__ float sq[64], sk[64], scal[64];
    int t = threadIdx.x;
    int p = blockIdx.x;                 // (R/8)*32 patches
    int prs = p >> 5, pc = p & 31;
    size_t SR = (size_t)R * 256;
    size_t sb = (size_t)(prs * 8) * 256 + pc * 8;
    const float* qg = h2s + sb;
    const float* kg = h2s + 128 * SR + sb;
    const float* vg = h2s + 256 * SR + sb;

    // phase 1: load q,k patch to LDS
    for (int it = 0; it < 8; it++) {
        int l4 = it * 256 + t;
        int c = l4 >> 4, r4 = l4 & 15;
        int i = r4 >> 1, jq = r4 & 1;
        *(float4*)&qs[c * CST + i * 8 + jq * 4] = *(const float4*)(qg + (size_t)c * SR + i * 256 + jq * 4);
        *(float4*)&ks[c * CST + i * 8 + jq * 4] = *(const float4*)(kg + (size_t)c * SR + i * 256 + jq * 4);
    }
    __syncthreads();

    // phase 1b: per-position channel sums of q^2, k^2
    {
        int pos = t & 63, grp = t >> 6;
        float s1 = 0.f, s2 = 0.f;
        for (int c = grp * 32; c < grp * 32 + 32; c++) {
            float a = qs[c * CST + pos]; s1 = fmaf(a, a, s1);
            float e = ks[c * CST + pos]; s2 = fmaf(e, e, s2);
        }
        part[grp * 64 + pos] = s1;
        part2[grp * 64 + pos] = s2;
    }
    __syncthreads();
    if (t < 64) {
        sq[t] = rsqrtf((part[t] + part[64 + t] + part[128 + t] + part[192 + t]) * (1.f / 128.f) + EPS);
    } else if (t < 128) {
        int u = t - 64;
        sk[u] = rsqrtf((part2[u] + part2[64 + u] + part2[128 + u] + part2[192 + u]) * (1.f / 128.f) + EPS);
    }
    __syncthreads();

    // phase 1c: RMS-scale + RoPE in place (pairs 2m,2m+1)
    for (int u = 0; u < 16; u++) {
        int task = u * 256 + t;
        int m = task >> 6, pos = task & 63;
        int i = pos >> 3, j = pos & 7;
        float2 cs = (m < 32) ? tab[(r0 + prs * 8 + i) * 32 + m]
                             : tab[(pc * 8 + j) * 32 + (m - 32)];
        float sqp = sq[pos], skp = sk[pos];
        float q0 = qs[(2 * m) * CST + pos], q1 = qs[(2 * m + 1) * CST + pos];
        float y0 = gq[2 * m] * q0 * sqp, y1 = gq[2 * m + 1] * q1 * sqp;
        qs[(2 * m) * CST + pos] = y0 * cs.x - y1 * cs.y;
        qs[(2 * m + 1) * CST + pos] = y1 * cs.x + y0 * cs.y;
        float k0 = ks[(2 * m) * CST + pos], k1 = ks[(2 * m + 1) * CST + pos];
        float z0 = gk[2 * m] * k0 * skp, z1 = gk[2 * m + 1] * k1 * skp;
        ks[(2 * m) * CST + pos] = z0 * cs.x - z1 * cs.y;
        ks[(2 * m + 1) * CST + pos] = z1 * cs.x + z0 * cs.y;
    }
    __syncthreads();

    // phase 2: circular conv rows -> registers (task = (c, m), 4 per thread; UNROLLED so creg
    // stays in VGPRs, not scratch)
    float creg[4][8];
#pragma unroll
    for (int g4 = 0; g4 < 4; g4++) {
        int task = g4 * 256 + t;
        int c = task >> 3, m = task & 7;
        float o8[8] = {0, 0, 0, 0, 0, 0, 0, 0};
#pragma unroll
        for (int i = 0; i < 8; i++) {
            const float* qr = &qs[c * CST + i * 8];
            float4 qa = *(const float4*)qr, qb = *(const float4*)(qr + 4);
            float qq[8] = {qa.x, qa.y, qa.z, qa.w, qb.x, qb.y, qb.z, qb.w};
            int kr = (m - i) & 7;
            const float* krp = &ks[c * CST + kr * 8];
            float4 ka = *(const float4*)krp, kb2 = *(const float4*)(krp + 4);
            float kk[8] = {ka.x, ka.y, ka.z, ka.w, kb2.x, kb2.y, kb2.z, kb2.w};
#pragma unroll
            for (int n = 0; n < 8; n++)
#pragma unroll
                for (int j = 0; j < 8; j++)
                    o8[n] = fmaf(qq[j], kk[(n - j) & 7], o8[n]);
        }
#pragma unroll
        for (int n = 0; n < 8; n++) creg[g4][n] = o8[n];
    }
    __syncthreads();

    // phase 3: store corr over qs
#pragma unroll
    for (int g4 = 0; g4 < 4; g4++) {
        int task = g4 * 256 + t;
        int c = task >> 3, m = task & 7;
        *(float4*)&qs[c * CST + m * 8] =
            make_float4(creg[g4][0], creg[g4][1], creg[g4][2], creg[g4][3]);
        *(float4*)&qs[c * CST + m * 8 + 4] =
            make_float4(creg[g4][4], creg[g4][5], creg[g4][6], creg[g4][7]);
    }
    __syncthreads();

    // phase 4: per-position sum of corr^2 over channels
    {
        int pos = t & 63, q4 = t >> 6;
        float ssum = 0.f;
        for (int c = q4 * 32; c < q4 * 32 + 32; c++) {
            float v = qs[c * CST + pos];
            ssum = fmaf(v, v, ssum);
        }
        part[q4 * 64 + pos] = ssum;
    }
    __syncthreads();
    if (t < 64) {
        float s = part[t] + part[64 + t] + part[128 + t] + part[192 + t];
        scal[t] = rsqrtf(s * (1.0f / 128.f) + EPS);
    }
    __syncthreads();

    // phase 5: tmod in place: qs[c][pos] = corr*scal[pos]*gn[c]*v[c][pos]
    for (int it = 0; it < 8; it++) {
        int l4 = it * 256 + t;
        int c = l4 >> 4, r4 = l4 & 15;
        int i = r4 >> 1, jq = r4 & 1;
        float4 vv = *(const float4*)(vg + (size_t)c * SR + i * 256 + jq * 4);
        float4 sc4 = *(const float4*)&scal[r4 * 4];
        float g = gn[c];
        float4 cu = *(float4*)&qs[c * CST + r4 * 4];
        cu.x = cu.x * sc4.x * g * vv.x;
        cu.y = cu.y * sc4.y * g * vv.y;
        cu.z = cu.z * sc4.z * g * vv.z;
        cu.w = cu.w * sc4.w * g * vv.w;
        *(float4*)&qs[c * CST + r4 * 4] = cu;
    }
    __syncthreads();

    // phase 6: project 128->64, stage to ks as out_s[pos*CST + o]
    {
        int o = t & 63, pg = t >> 6;
        float acc[16];
#pragma unroll
        for (int u = 0; u < 16; u++) acc[u] = 0.f;
        for (int c = 0; c < C2; c++) {
            float w = wpt[c * 64 + o];
            const float* tp = &qs[c * CST + pg * 16];
#pragma unroll
            for (int u4 = 0; u4 < 4; u4++) {
                float4 tv = *(const float4*)(tp + u4 * 4);
                acc[u4 * 4 + 0] = fmaf(w, tv.x, acc[u4 * 4 + 0]);
                acc[u4 * 4 + 1] = fmaf(w, tv.y, acc[u4 * 4 + 1]);
                acc[u4 * 4 + 2] = fmaf(w, tv.z, acc[u4 * 4 + 2]);
                acc[u4 * 4 + 3] = fmaf(w, tv.w, acc[u4 * 4 + 3]);
            }
        }
#pragma unroll
        for (int u = 0; u < 16; u++) ks[(pg * 16 + u) * CST + o] = acc[u];
    }
    __syncthreads();

    // phase 7: coalesced out write
    float* og = outb + (size_t)r0 * 256 + sb;
    for (int it = 0; it < 4; it++) {
        int l4 = it * 256 + t;
        int o = l4 >> 4, r4 = l4 & 15;
        int i = r4 >> 1, jq = r4 & 1;
        int p0 = i * 8 + jq * 4;
        float4 vv = make_float4(ks[(p0 + 0) * CST + o], ks[(p0 + 1) * CST + o],
                                ks[(p0 + 2) * CST + o], ks[(p0 + 3) * CST + o]);
        *(float4*)(og + (size_t)o * HW + i * 256 + jq * 4) = vv;
    }
}

extern "C" void kernel_launch(void* const* d_in, const int* in_sizes, int n_in,
                              void* d_out, int out_size, void* d_ws, size_t ws_size,
                              hipStream_t stream) {
    const float* x   = (const float*)d_in[0];
    const float* wh  = (const float*)d_in[1];
    const float* wdw = (const float*)d_in[2];
    const float* wp  = (const float*)d_in[3];
    const float* gn  = (const float*)d_in[4];
    const float* gq  = (const float*)d_in[5];
    const float* gk  = (const float*)d_in[6];
    float* out = (float*)d_out;

    // ws layout (floats): tab[16384] | wpt[8192] | h2s[384 * R * 256]
    size_t avail = ws_size / 4;
    if (avail < (size_t)24576 + (size_t)C6 * 8 * 256) return;  // need at least R=8
    size_t rows_cap = (avail - 24576) / ((size_t)C6 * 256);
    int R = (rows_cap >= 256) ? 256 : (int)(rows_cap & ~(size_t)7);

    float* ws = (float*)d_ws;
    float2* tab = (float2*)ws;
    float* wpt  = ws + 16384;
    float* h2s  = ws + 24576;

    k_tab<<<32, 256, 0, stream>>>(tab);
    k_wt<<<32, 256, 0, stream>>>(wp, wpt);
    for (int b = 0; b < BB; b++) {
        const float* xb = x + (size_t)b * Cc * HW;
        float* outb = out + (size_t)b * Cc * HW;
        for (int r0 = 0; r0 < 256; r0 += R) {
            int Rc = (256 - r0 < R) ? (256 - r0) : R;
            int tiles_y = (Rc + 13) / 14;
            k_expdw<<<19 * tiles_y * OSPLIT, 256, 0, stream>>>(xb, wh, wdw, h2s, r0, Rc, tiles_y);
            k_patch<<<(Rc / 8) * 32, 256, 0, stream>>>(h2s, gq, gk, gn, wpt, tab, outb, r0, Rc);
        }
    }
}